// Round 1
// baseline (673.321 us; speedup 1.0000x reference)
//
#include <hip/hip_runtime.h>

// ---------------------------------------------------------------------------
// VQEmbeddingEMA forward on MI355X (gfx950), fp32.
//   N = 32*2048 = 65536 tokens, D = 64, K = 1024 codes.
// Outputs (flat, concatenated):
//   [0)            st_quantized   65536*64
//   [4194304)      commitment_loss (1)
//   [4194305)      codebook_loss   (1)
//   [4194306)      perplexity      (1)
//   [4194307)      new_embedding   1024*64
//   [4259843)      new_count       1024
//   [4260867)      new_weight      1024*64
//   [4326403)      new_usage       1024
// ---------------------------------------------------------------------------

#define N_TOK   65536
#define DIM     64
#define KCODES  1024

#define Q_OFF   0
#define SC_OFF  4194304
#define NE_OFF  4194307
#define NC_OFF  4259843
#define NW_OFF  4260867
#define NU_OFF  4326403

// ws layout (floats): counts[1024] @0, dw[65536] @1024, loss[1] @66560,
//                     hn[1024] @66564   (zero region = first 66561 floats)
#define WS_COUNTS 0
#define WS_DW     1024
#define WS_LOSS   66560
#define WS_HN     66564

// 0.5 * |e_k|^2 per code
__global__ __launch_bounds__(256) void hn_kernel(const float* __restrict__ emb,
                                                 float* __restrict__ hn) {
    int k = blockIdx.x * 256 + threadIdx.x;   // grid 4x256 -> 1024
    const float4* e4 = reinterpret_cast<const float4*>(emb) + (size_t)k * 16;
    float4 a = make_float4(0.f, 0.f, 0.f, 0.f);
#pragma unroll
    for (int i = 0; i < 16; ++i) {
        float4 e = e4[i];
        a.x = fmaf(e.x, e.x, a.x);
        a.y = fmaf(e.y, e.y, a.y);
        a.z = fmaf(e.z, e.z, a.z);
        a.w = fmaf(e.w, e.w, a.w);
    }
    hn[k] = 0.5f * ((a.x + a.y) + (a.z + a.w));
}

// One token per thread: argmin_k (0.5|e|^2 - x.e), then fused epilogue:
// quantized write, loss partial, counts/dw atomics.
__global__ __launch_bounds__(256) void assign_kernel(
    const float* __restrict__ x, const float* __restrict__ emb,
    const float* __restrict__ hn, float* __restrict__ counts,
    float* __restrict__ dw, float* __restrict__ loss_sum,
    float* __restrict__ qout) {
    __shared__ float4 se[2048];   // 128 codes x 16 float4 = 32 KB

    const int tok = blockIdx.x * 256 + threadIdx.x;
    const float4* x4  = reinterpret_cast<const float4*>(x) + (size_t)tok * 16;
    const float4* e4g = reinterpret_cast<const float4*>(emb);

    float4 xr[16];
#pragma unroll
    for (int i = 0; i < 16; ++i) xr[i] = x4[i];

    float best = 3.0e38f;
    int bidx = 0;

    for (int c = 0; c < 8; ++c) {
        __syncthreads();
#pragma unroll
        for (int i = 0; i < 8; ++i)
            se[threadIdx.x + i * 256] = e4g[c * 2048 + threadIdx.x + i * 256];
        __syncthreads();

        const int kbase = c * 128;
        for (int kk = 0; kk < 128; kk += 2) {
            const float4* e0 = &se[(kk)     * 16];
            const float4* e1 = &se[(kk + 1) * 16];
            float4 a = make_float4(0.f, 0.f, 0.f, 0.f);
            float4 b = make_float4(0.f, 0.f, 0.f, 0.f);
#pragma unroll
            for (int i = 0; i < 16; ++i) {
                float4 xv = xr[i];
                float4 ea = e0[i];
                float4 eb = e1[i];
                a.x = fmaf(xv.x, ea.x, a.x);
                a.y = fmaf(xv.y, ea.y, a.y);
                a.z = fmaf(xv.z, ea.z, a.z);
                a.w = fmaf(xv.w, ea.w, a.w);
                b.x = fmaf(xv.x, eb.x, b.x);
                b.y = fmaf(xv.y, eb.y, b.y);
                b.z = fmaf(xv.z, eb.z, b.z);
                b.w = fmaf(xv.w, eb.w, b.w);
            }
            float d0 = (a.x + a.y) + (a.z + a.w);
            float d1 = (b.x + b.y) + (b.z + b.w);
            float s0 = hn[kbase + kk]     - d0;
            float s1 = hn[kbase + kk + 1] - d1;
            // ascending k + strict < keeps the first (lowest-k) minimum,
            // matching jnp.argmin tie-breaking.
            if (s0 < best) { best = s0; bidx = kbase + kk; }
            if (s1 < best) { best = s1; bidx = kbase + kk + 1; }
        }
    }

    // ---- epilogue ----
    const float4* eb4 = e4g + (size_t)bidx * 16;
    float4* q4 = reinterpret_cast<float4*>(qout) + (size_t)tok * 16;
    float lsum = 0.0f;
#pragma unroll
    for (int i = 0; i < 16; ++i) {
        float4 e = eb4[i];
        q4[i] = e;
        float d0 = xr[i].x - e.x; lsum = fmaf(d0, d0, lsum);
        float d1 = xr[i].y - e.y; lsum = fmaf(d1, d1, lsum);
        float d2 = xr[i].z - e.z; lsum = fmaf(d2, d2, lsum);
        float d3 = xr[i].w - e.w; lsum = fmaf(d3, d3, lsum);
    }

    atomicAdd(&counts[bidx], 1.0f);

    float* dwp = dw + (size_t)bidx * 64;
#pragma unroll
    for (int i = 0; i < 16; ++i) {
        atomicAdd(dwp + 4 * i + 0, xr[i].x);
        atomicAdd(dwp + 4 * i + 1, xr[i].y);
        atomicAdd(dwp + 4 * i + 2, xr[i].z);
        atomicAdd(dwp + 4 * i + 3, xr[i].w);
    }

#pragma unroll
    for (int off = 32; off; off >>= 1) lsum += __shfl_down(lsum, off, 64);
    if ((threadIdx.x & 63) == 0) atomicAdd(loss_sum, lsum);
}

// counts-based outputs: new_count, new_usage, scalars (one block, k = tid)
__global__ __launch_bounds__(1024) void finalize1(
    const float* __restrict__ counts, const float* __restrict__ loss_sum,
    const float* __restrict__ ema_count, const float* __restrict__ usage,
    float* __restrict__ out) {
    const int k = threadIdx.x;
    const float cnt = counts[k];
    const float raw = 0.999f * ema_count[k] + 0.001f * cnt;
    const float p = cnt * (1.0f / 65536.0f);
    const float term = p * logf(p + 1e-10f);

    float v1 = raw, v2 = term;
#pragma unroll
    for (int off = 32; off; off >>= 1) {
        v1 += __shfl_down(v1, off, 64);
        v2 += __shfl_down(v2, off, 64);
    }
    __shared__ float r1[16], r2[16];
    __shared__ float s_n, s_plog;
    if ((k & 63) == 0) { r1[k >> 6] = v1; r2[k >> 6] = v2; }
    __syncthreads();
    if (k < 64) {
        float a = (k < 16) ? r1[k] : 0.0f;
        float b = (k < 16) ? r2[k] : 0.0f;
#pragma unroll
        for (int off = 8; off; off >>= 1) {
            a += __shfl_down(a, off, 64);
            b += __shfl_down(b, off, 64);
        }
        if (k == 0) { s_n = a; s_plog = b; }
    }
    __syncthreads();

    const float n = s_n;
    const float smoothed = (raw + 1e-5f) / (n + 1024.0f * 1e-5f) * n;
    out[NC_OFF + k] = smoothed;
    out[NU_OFF + k] = (usage[k] + (cnt > 0.0f ? 1.0f : 0.0f)) * 0.5f;
    if (k == 0) {
        const float lm = loss_sum[0] * (1.0f / 4194304.0f);
        out[SC_OFF + 0] = 0.25f * lm;   // commitment_loss
        out[SC_OFF + 1] = lm;           // codebook_loss
        out[SC_OFF + 2] = expf(-s_plog);// perplexity
    }
}

// new_weight / new_embedding, coalesced elementwise (offsets not 16B aligned
// in out, so scalar fp32 accesses).
__global__ __launch_bounds__(256) void finalize2(
    const float* __restrict__ dw, const float* __restrict__ ema_weight,
    const float* __restrict__ new_count, float* __restrict__ new_weight,
    float* __restrict__ new_embedding) {
    int i = blockIdx.x * 256 + threadIdx.x;   // grid 256x256 -> 65536
    float w = 0.999f * ema_weight[i] + 0.001f * dw[i];
    new_weight[i] = w;
    new_embedding[i] = w / new_count[i >> 6];
}

extern "C" void kernel_launch(void* const* d_in, const int* in_sizes, int n_in,
                              void* d_out, int out_size, void* d_ws, size_t ws_size,
                              hipStream_t stream) {
    const float* x          = (const float*)d_in[0];
    const float* emb        = (const float*)d_in[1];
    const float* ema_count  = (const float*)d_in[2];
    const float* ema_weight = (const float*)d_in[3];
    const float* usage      = (const float*)d_in[4];
    float* out = (float*)d_out;
    float* ws  = (float*)d_ws;

    float* counts = ws + WS_COUNTS;
    float* dw     = ws + WS_DW;
    float* loss   = ws + WS_LOSS;
    float* hn     = ws + WS_HN;

    // ws is re-poisoned to 0xAA before every timed launch -> zero it here.
    hipMemsetAsync(ws, 0, 66561 * sizeof(float), stream);

    hn_kernel<<<4, 256, 0, stream>>>(emb, hn);
    assign_kernel<<<256, 256, 0, stream>>>(x, emb, hn, counts, dw, loss,
                                           out + Q_OFF);
    finalize1<<<1, 1024, 0, stream>>>(counts, loss, ema_count, usage, out);
    finalize2<<<256, 256, 0, stream>>>(dw, ema_weight, out + NC_OFF,
                                       out + NW_OFF, out + NE_OFF);
}

// Round 4
// 564.213 us; speedup vs baseline: 1.1934x; 1.1934x over previous
//
#include <hip/hip_runtime.h>

// ---------------------------------------------------------------------------
// VQEmbeddingEMA forward on MI355X (gfx950), fp32.
//   N = 32*2048 = 65536 tokens, D = 64, K = 1024 codes.
// Round 2 kernel (resubmit #2; rounds 2-3 hit GPUAcquisitionTimeout):
// distance search via wave-uniform scalar loads (SMEM pipe) instead of LDS;
// 4-way code split across blocks for 4 waves/SIMD; merge kernel combines
// partials and runs the epilogue.
// ---------------------------------------------------------------------------

#define N_TOK   65536
#define KCODES  1024

#define Q_OFF   0
#define SC_OFF  4194304
#define NE_OFF  4194307
#define NC_OFF  4259843
#define NW_OFF  4260867
#define NU_OFF  4326403

// ws layout (floats)
#define WS_COUNTS 0
#define WS_DW     1024
#define WS_LOSS   66560
#define WS_HN     66564
#define WS_PS     67588          // partial scores  [4][65536]
#define WS_PI     329732         // partial indices [4][65536]

// 0.5 * |e_k|^2 per code
__global__ __launch_bounds__(256) void hn_kernel(const float* __restrict__ emb,
                                                 float* __restrict__ hn) {
    int k = blockIdx.x * 256 + threadIdx.x;   // grid 4x256 -> 1024
    const float4* e4 = reinterpret_cast<const float4*>(emb) + (size_t)k * 16;
    float4 a = make_float4(0.f, 0.f, 0.f, 0.f);
#pragma unroll
    for (int i = 0; i < 16; ++i) {
        float4 e = e4[i];
        a.x = fmaf(e.x, e.x, a.x);
        a.y = fmaf(e.y, e.y, a.y);
        a.z = fmaf(e.z, e.z, a.z);
        a.w = fmaf(e.w, e.w, a.w);
    }
    hn[k] = 0.5f * ((a.x + a.y) + (a.z + a.w));
}

// One token per thread, 256 codes per block (4-way K split).
// e / hn accesses are wave-uniform -> scalar loads on the SMEM pipe.
__global__ __launch_bounds__(256) void assign_kernel(
    const float* __restrict__ x, const float* __restrict__ emb,
    const float* __restrict__ hn, float* __restrict__ pscore,
    int* __restrict__ pidx) {
    const int part  = blockIdx.x & 3;
    const int tok   = (blockIdx.x >> 2) * 256 + threadIdx.x;
    const int kbase = part * 256;

    const float4* __restrict__ x4 =
        reinterpret_cast<const float4*>(x) + (size_t)tok * 16;
    float4 xr[16];
#pragma unroll
    for (int i = 0; i < 16; ++i) xr[i] = x4[i];

    const float4* __restrict__ e4 =
        reinterpret_cast<const float4*>(emb) + (size_t)kbase * 16;
    const float* __restrict__ hb = hn + kbase;

    float best = 3.0e38f;
    int bloc = 0;

    for (int kk = 0; kk < 256; kk += 2) {
        const float4* __restrict__ e0 = e4 + (size_t)kk * 16;
        float4 a = make_float4(0.f, 0.f, 0.f, 0.f);
        float4 b = make_float4(0.f, 0.f, 0.f, 0.f);
#pragma unroll
        for (int i = 0; i < 16; ++i) {
            float4 xv = xr[i];
            float4 ea = e0[i];        // uniform -> s_load
            float4 eb = e0[16 + i];   // uniform -> s_load
            a.x = fmaf(xv.x, ea.x, a.x);
            a.y = fmaf(xv.y, ea.y, a.y);
            a.z = fmaf(xv.z, ea.z, a.z);
            a.w = fmaf(xv.w, ea.w, a.w);
            b.x = fmaf(xv.x, eb.x, b.x);
            b.y = fmaf(xv.y, eb.y, b.y);
            b.z = fmaf(xv.z, eb.z, b.z);
            b.w = fmaf(xv.w, eb.w, b.w);
        }
        float d0 = (a.x + a.y) + (a.z + a.w);
        float d1 = (b.x + b.y) + (b.z + b.w);
        float s0 = hb[kk]     - d0;
        float s1 = hb[kk + 1] - d1;
        // ascending k + strict < == first-minimum tie-break (jnp.argmin)
        if (s0 < best) { best = s0; bloc = kk; }
        if (s1 < best) { best = s1; bloc = kk + 1; }
    }

    pscore[part * N_TOK + tok] = best;
    pidx  [part * N_TOK + tok] = kbase + bloc;
}

// Combine 4 partial candidates, then fused epilogue:
// quantized write, loss partial, counts/dw atomics.
__global__ __launch_bounds__(256) void merge_kernel(
    const float* __restrict__ x, const float* __restrict__ emb,
    const float* __restrict__ pscore, const int* __restrict__ pidx,
    float* __restrict__ counts, float* __restrict__ dw,
    float* __restrict__ loss_sum, float* __restrict__ qout) {
    const int tok = blockIdx.x * 256 + threadIdx.x;

    float bs = pscore[tok];
    int   bi = pidx[tok];
#pragma unroll
    for (int h = 1; h < 4; ++h) {
        float s  = pscore[h * N_TOK + tok];
        int   i2 = pidx[h * N_TOK + tok];
        // later h always has larger idx, so strict < keeps lowest-idx min
        if (s < bs) { bs = s; bi = i2; }
    }

    const float4* x4 = reinterpret_cast<const float4*>(x) + (size_t)tok * 16;
    const float4* eb4 = reinterpret_cast<const float4*>(emb) + (size_t)bi * 16;
    float4* q4 = reinterpret_cast<float4*>(qout) + (size_t)tok * 16;

    float lsum = 0.0f;
    float xr[64];
#pragma unroll
    for (int i = 0; i < 16; ++i) {
        float4 xv = x4[i];
        float4 e  = eb4[i];
        q4[i] = e;
        float d0 = xv.x - e.x; lsum = fmaf(d0, d0, lsum);
        float d1 = xv.y - e.y; lsum = fmaf(d1, d1, lsum);
        float d2 = xv.z - e.z; lsum = fmaf(d2, d2, lsum);
        float d3 = xv.w - e.w; lsum = fmaf(d3, d3, lsum);
        xr[4 * i + 0] = xv.x; xr[4 * i + 1] = xv.y;
        xr[4 * i + 2] = xv.z; xr[4 * i + 3] = xv.w;
    }

    atomicAdd(&counts[bi], 1.0f);

    float* dwp = dw + (size_t)bi * 64;
#pragma unroll
    for (int i = 0; i < 64; ++i) atomicAdd(dwp + i, xr[i]);

#pragma unroll
    for (int off = 32; off; off >>= 1) lsum += __shfl_down(lsum, off, 64);
    if ((threadIdx.x & 63) == 0) atomicAdd(loss_sum, lsum);
}

// counts-based outputs: new_count, new_usage, scalars (one block, k = tid)
__global__ __launch_bounds__(1024) void finalize1(
    const float* __restrict__ counts, const float* __restrict__ loss_sum,
    const float* __restrict__ ema_count, const float* __restrict__ usage,
    float* __restrict__ out) {
    const int k = threadIdx.x;
    const float cnt = counts[k];
    const float raw = 0.999f * ema_count[k] + 0.001f * cnt;
    const float p = cnt * (1.0f / 65536.0f);
    const float term = p * logf(p + 1e-10f);

    float v1 = raw, v2 = term;
#pragma unroll
    for (int off = 32; off; off >>= 1) {
        v1 += __shfl_down(v1, off, 64);
        v2 += __shfl_down(v2, off, 64);
    }
    __shared__ float r1[16], r2[16];
    __shared__ float s_n, s_plog;
    if ((k & 63) == 0) { r1[k >> 6] = v1; r2[k >> 6] = v2; }
    __syncthreads();
    if (k < 64) {
        float a = (k < 16) ? r1[k] : 0.0f;
        float b = (k < 16) ? r2[k] : 0.0f;
#pragma unroll
        for (int off = 8; off; off >>= 1) {
            a += __shfl_down(a, off, 64);
            b += __shfl_down(b, off, 64);
        }
        if (k == 0) { s_n = a; s_plog = b; }
    }
    __syncthreads();

    const float n = s_n;
    const float smoothed = (raw + 1e-5f) / (n + 1024.0f * 1e-5f) * n;
    out[NC_OFF + k] = smoothed;
    out[NU_OFF + k] = (usage[k] + (cnt > 0.0f ? 1.0f : 0.0f)) * 0.5f;
    if (k == 0) {
        const float lm = loss_sum[0] * (1.0f / 4194304.0f);
        out[SC_OFF + 0] = 0.25f * lm;    // commitment_loss
        out[SC_OFF + 1] = lm;            // codebook_loss
        out[SC_OFF + 2] = expf(-s_plog); // perplexity
    }
}

// new_weight / new_embedding, coalesced elementwise.
__global__ __launch_bounds__(256) void finalize2(
    const float* __restrict__ dw, const float* __restrict__ ema_weight,
    const float* __restrict__ new_count, float* __restrict__ new_weight,
    float* __restrict__ new_embedding) {
    int i = blockIdx.x * 256 + threadIdx.x;   // grid 256x256 -> 65536
    float w = 0.999f * ema_weight[i] + 0.001f * dw[i];
    new_weight[i] = w;
    new_embedding[i] = w / new_count[i >> 6];
}

extern "C" void kernel_launch(void* const* d_in, const int* in_sizes, int n_in,
                              void* d_out, int out_size, void* d_ws, size_t ws_size,
                              hipStream_t stream) {
    const float* x          = (const float*)d_in[0];
    const float* emb        = (const float*)d_in[1];
    const float* ema_count  = (const float*)d_in[2];
    const float* ema_weight = (const float*)d_in[3];
    const float* usage      = (const float*)d_in[4];
    float* out = (float*)d_out;
    float* ws  = (float*)d_ws;

    float* counts = ws + WS_COUNTS;
    float* dw     = ws + WS_DW;
    float* loss   = ws + WS_LOSS;
    float* hn     = ws + WS_HN;
    float* ps     = ws + WS_PS;
    int*   pi     = (int*)(ws + WS_PI);

    // ws is re-poisoned to 0xAA before every timed launch -> zero the
    // accumulated regions (counts + dw + loss). hn/ps/pi are fully written.
    hipMemsetAsync(ws, 0, 66561 * sizeof(float), stream);

    hn_kernel<<<4, 256, 0, stream>>>(emb, hn);
    assign_kernel<<<1024, 256, 0, stream>>>(x, emb, hn, ps, pi);
    merge_kernel<<<256, 256, 0, stream>>>(x, emb, ps, pi, counts, dw, loss,
                                          out + Q_OFF);
    finalize1<<<1, 1024, 0, stream>>>(counts, loss, ema_count, usage, out);
    finalize2<<<256, 256, 0, stream>>>(dw, ema_weight, out + NC_OFF,
                                       out + NW_OFF, out + NE_OFF);
}

// Round 6
// 344.082 us; speedup vs baseline: 1.9569x; 1.6398x over previous
//
#include <hip/hip_runtime.h>

// ---------------------------------------------------------------------------
// VQEmbeddingEMA forward on MI355X (gfx950), fp32.
//   N = 32*2048 = 65536 tokens, D = 64, K = 1024 codes.
// Round 5 kernel (resubmit; round-5 bench hit GPUAcquisitionTimeout):
// kill the dw atomics (320us of atomic serialization, VALUBusy 0.1%).
// merge writes idx[tok]; a scan-gather kernel (block per code, ballot over
// the L2-resident idx array) computes the segment sum with plain stores.
// ---------------------------------------------------------------------------

#define N_TOK   65536
#define KCODES  1024

#define Q_OFF   0
#define SC_OFF  4194304
#define NE_OFF  4194307
#define NC_OFF  4259843
#define NW_OFF  4260867
#define NU_OFF  4326403

// ws layout (floats)
#define WS_COUNTS 0              // [1024]  (atomic, zeroed)
#define WS_LOSS   1024           // [1]     (atomic, zeroed)
#define WS_HN     1028           // [1024]
#define WS_DW     2052           // [65536]
#define WS_IDX    67588          // [65536] int
#define WS_PS     133124         // [4][65536] partial scores
#define WS_PI     395268         // [4][65536] partial indices (int)

// 0.5 * |e_k|^2 per code
__global__ __launch_bounds__(256) void hn_kernel(const float* __restrict__ emb,
                                                 float* __restrict__ hn) {
    int k = blockIdx.x * 256 + threadIdx.x;   // grid 4x256 -> 1024
    const float4* e4 = reinterpret_cast<const float4*>(emb) + (size_t)k * 16;
    float4 a = make_float4(0.f, 0.f, 0.f, 0.f);
#pragma unroll
    for (int i = 0; i < 16; ++i) {
        float4 e = e4[i];
        a.x = fmaf(e.x, e.x, a.x);
        a.y = fmaf(e.y, e.y, a.y);
        a.z = fmaf(e.z, e.z, a.z);
        a.w = fmaf(e.w, e.w, a.w);
    }
    hn[k] = 0.5f * ((a.x + a.y) + (a.z + a.w));
}

// One token per thread, 256 codes per block (4-way K split).
// e / hn accesses are wave-uniform -> scalar loads on the SMEM pipe.
__global__ __launch_bounds__(256) void assign_kernel(
    const float* __restrict__ x, const float* __restrict__ emb,
    const float* __restrict__ hn, float* __restrict__ pscore,
    int* __restrict__ pidx) {
    const int part  = blockIdx.x & 3;
    const int tok   = (blockIdx.x >> 2) * 256 + threadIdx.x;
    const int kbase = part * 256;

    const float4* __restrict__ x4 =
        reinterpret_cast<const float4*>(x) + (size_t)tok * 16;
    float4 xr[16];
#pragma unroll
    for (int i = 0; i < 16; ++i) xr[i] = x4[i];

    const float4* __restrict__ e4 =
        reinterpret_cast<const float4*>(emb) + (size_t)kbase * 16;
    const float* __restrict__ hb = hn + kbase;

    float best = 3.0e38f;
    int bloc = 0;

    for (int kk = 0; kk < 256; kk += 2) {
        const float4* __restrict__ e0 = e4 + (size_t)kk * 16;
        float4 a = make_float4(0.f, 0.f, 0.f, 0.f);
        float4 b = make_float4(0.f, 0.f, 0.f, 0.f);
#pragma unroll
        for (int i = 0; i < 16; ++i) {
            float4 xv = xr[i];
            float4 ea = e0[i];        // uniform -> s_load
            float4 eb = e0[16 + i];   // uniform -> s_load
            a.x = fmaf(xv.x, ea.x, a.x);
            a.y = fmaf(xv.y, ea.y, a.y);
            a.z = fmaf(xv.z, ea.z, a.z);
            a.w = fmaf(xv.w, ea.w, a.w);
            b.x = fmaf(xv.x, eb.x, b.x);
            b.y = fmaf(xv.y, eb.y, b.y);
            b.z = fmaf(xv.z, eb.z, b.z);
            b.w = fmaf(xv.w, eb.w, b.w);
        }
        float d0 = (a.x + a.y) + (a.z + a.w);
        float d1 = (b.x + b.y) + (b.z + b.w);
        float s0 = hb[kk]     - d0;
        float s1 = hb[kk + 1] - d1;
        // ascending k + strict < == first-minimum tie-break (jnp.argmin)
        if (s0 < best) { best = s0; bloc = kk; }
        if (s1 < best) { best = s1; bloc = kk + 1; }
    }

    pscore[part * N_TOK + tok] = best;
    pidx  [part * N_TOK + tok] = kbase + bloc;
}

// Combine 4 partial candidates; write idx, quantized, loss, counts.
// NO per-element dw atomics anymore.
__global__ __launch_bounds__(256) void merge_kernel(
    const float* __restrict__ x, const float* __restrict__ emb,
    const float* __restrict__ pscore, const int* __restrict__ pidx,
    float* __restrict__ counts, int* __restrict__ idx,
    float* __restrict__ loss_sum, float* __restrict__ qout) {
    const int tok = blockIdx.x * 256 + threadIdx.x;

    float bs = pscore[tok];
    int   bi = pidx[tok];
#pragma unroll
    for (int h = 1; h < 4; ++h) {
        float s  = pscore[h * N_TOK + tok];
        int   i2 = pidx[h * N_TOK + tok];
        // later h always has larger idx, so strict < keeps lowest-idx min
        if (s < bs) { bs = s; bi = i2; }
    }
    idx[tok] = bi;

    const float4* x4  = reinterpret_cast<const float4*>(x) + (size_t)tok * 16;
    const float4* eb4 = reinterpret_cast<const float4*>(emb) + (size_t)bi * 16;
    float4* q4 = reinterpret_cast<float4*>(qout) + (size_t)tok * 16;

    float lsum = 0.0f;
#pragma unroll
    for (int i = 0; i < 16; ++i) {
        float4 xv = x4[i];
        float4 e  = eb4[i];
        q4[i] = e;
        float d0 = xv.x - e.x; lsum = fmaf(d0, d0, lsum);
        float d1 = xv.y - e.y; lsum = fmaf(d1, d1, lsum);
        float d2 = xv.z - e.z; lsum = fmaf(d2, d2, lsum);
        float d3 = xv.w - e.w; lsum = fmaf(d3, d3, lsum);
    }

    atomicAdd(&counts[bi], 1.0f);

#pragma unroll
    for (int off = 32; off; off >>= 1) lsum += __shfl_down(lsum, off, 64);
    if ((threadIdx.x & 63) == 0) atomicAdd(loss_sum, lsum);
}

// Segment-sum via scan-gather: block k sums x rows of tokens with idx==k.
// idx is L2-resident (256 KB); each x row is read exactly once device-wide.
// Ascending-token accumulation order matches jax.ops.segment_sum.
__global__ __launch_bounds__(256) void gather_kernel(
    const float* __restrict__ x, const int* __restrict__ idx,
    float* __restrict__ dw) {
    const int k    = blockIdx.x;          // code
    const int wave = threadIdx.x >> 6;    // 0..3
    const int lane = threadIdx.x & 63;    // dimension

    float acc = 0.0f;
    const int begin = wave * (N_TOK / 4);
    const int end   = begin + (N_TOK / 4);
    for (int base = begin; base < end; base += 64) {
        int mi = idx[base + lane];
        unsigned long long m = __ballot(mi == k);
        while (m) {
            int b = __ffsll((long long)m) - 1;
            m &= m - 1;
            acc += x[(size_t)(base + b) * 64 + lane];
        }
    }

    __shared__ float red[4][64];
    red[wave][lane] = acc;
    __syncthreads();
    if (wave == 0) {
        float s = (red[0][lane] + red[1][lane]) + (red[2][lane] + red[3][lane]);
        dw[(size_t)k * 64 + lane] = s;
    }
}

// counts-based outputs: new_count, new_usage, scalars (one block, k = tid)
__global__ __launch_bounds__(1024) void finalize1(
    const float* __restrict__ counts, const float* __restrict__ loss_sum,
    const float* __restrict__ ema_count, const float* __restrict__ usage,
    float* __restrict__ out) {
    const int k = threadIdx.x;
    const float cnt = counts[k];
    const float raw = 0.999f * ema_count[k] + 0.001f * cnt;
    const float p = cnt * (1.0f / 65536.0f);
    const float term = p * logf(p + 1e-10f);

    float v1 = raw, v2 = term;
#pragma unroll
    for (int off = 32; off; off >>= 1) {
        v1 += __shfl_down(v1, off, 64);
        v2 += __shfl_down(v2, off, 64);
    }
    __shared__ float r1[16], r2[16];
    __shared__ float s_n, s_plog;
    if ((k & 63) == 0) { r1[k >> 6] = v1; r2[k >> 6] = v2; }
    __syncthreads();
    if (k < 64) {
        float a = (k < 16) ? r1[k] : 0.0f;
        float b = (k < 16) ? r2[k] : 0.0f;
#pragma unroll
        for (int off = 8; off; off >>= 1) {
            a += __shfl_down(a, off, 64);
            b += __shfl_down(b, off, 64);
        }
        if (k == 0) { s_n = a; s_plog = b; }
    }
    __syncthreads();

    const float n = s_n;
    const float smoothed = (raw + 1e-5f) / (n + 1024.0f * 1e-5f) * n;
    out[NC_OFF + k] = smoothed;
    out[NU_OFF + k] = (usage[k] + (cnt > 0.0f ? 1.0f : 0.0f)) * 0.5f;
    if (k == 0) {
        const float lm = loss_sum[0] * (1.0f / 4194304.0f);
        out[SC_OFF + 0] = 0.25f * lm;    // commitment_loss
        out[SC_OFF + 1] = lm;            // codebook_loss
        out[SC_OFF + 2] = expf(-s_plog); // perplexity
    }
}

// new_weight / new_embedding, coalesced elementwise.
__global__ __launch_bounds__(256) void finalize2(
    const float* __restrict__ dw, const float* __restrict__ ema_weight,
    const float* __restrict__ new_count, float* __restrict__ new_weight,
    float* __restrict__ new_embedding) {
    int i = blockIdx.x * 256 + threadIdx.x;   // grid 256x256 -> 65536
    float w = 0.999f * ema_weight[i] + 0.001f * dw[i];
    new_weight[i] = w;
    new_embedding[i] = w / new_count[i >> 6];
}

extern "C" void kernel_launch(void* const* d_in, const int* in_sizes, int n_in,
                              void* d_out, int out_size, void* d_ws, size_t ws_size,
                              hipStream_t stream) {
    const float* x          = (const float*)d_in[0];
    const float* emb        = (const float*)d_in[1];
    const float* ema_count  = (const float*)d_in[2];
    const float* ema_weight = (const float*)d_in[3];
    const float* usage      = (const float*)d_in[4];
    float* out = (float*)d_out;
    float* ws  = (float*)d_ws;

    float* counts = ws + WS_COUNTS;
    float* loss   = ws + WS_LOSS;
    float* hn     = ws + WS_HN;
    float* dw     = ws + WS_DW;
    int*   idx    = (int*)(ws + WS_IDX);
    float* ps     = ws + WS_PS;
    int*   pi     = (int*)(ws + WS_PI);

    // ws is re-poisoned to 0xAA before every timed launch -> zero the
    // atomic regions (counts + loss). Everything else is fully written.
    hipMemsetAsync(ws, 0, 1025 * sizeof(float), stream);

    hn_kernel<<<4, 256, 0, stream>>>(emb, hn);
    assign_kernel<<<1024, 256, 0, stream>>>(x, emb, hn, ps, pi);
    merge_kernel<<<256, 256, 0, stream>>>(x, emb, ps, pi, counts, idx, loss,
                                          out + Q_OFF);
    gather_kernel<<<1024, 256, 0, stream>>>(x, idx, dw);
    finalize1<<<1, 1024, 0, stream>>>(counts, loss, ema_count, usage, out);
    finalize2<<<256, 256, 0, stream>>>(dw, ema_weight, out + NC_OFF,
                                       out + NW_OFF, out + NE_OFF);
}

// Round 7
// 324.866 us; speedup vs baseline: 2.0726x; 1.0592x over previous
//
#include <hip/hip_runtime.h>

// ---------------------------------------------------------------------------
// VQEmbeddingEMA forward on MI355X (gfx950), fp32.
//   N = 32*2048 = 65536 tokens, D = 64, K = 1024 codes.
// Round 7: assign with 2 tokens/thread (double FMA per SMEM chunk; VALUBusy
// was 40% on 1-token), 8-way K split, XCD-co-located parts; gather with 8
// waves + unrolled independent idx loads (break dependent-load chain).
// ---------------------------------------------------------------------------

#define N_TOK   65536
#define KCODES  1024

#define Q_OFF   0
#define SC_OFF  4194304
#define NE_OFF  4194307
#define NC_OFF  4259843
#define NW_OFF  4260867
#define NU_OFF  4326403

// ws layout (floats)
#define WS_COUNTS 0              // [1024]  (atomic, zeroed)
#define WS_LOSS   1024           // [1]     (atomic, zeroed)
#define WS_HN     1028           // [1024]
#define WS_DW     2052           // [65536]
#define WS_IDX    67588          // [65536] int
#define WS_PS     133124         // [8][65536] partial scores
#define WS_PI     657412         // [8][65536] partial indices (int)

// 0.5 * |e_k|^2 per code
__global__ __launch_bounds__(256) void hn_kernel(const float* __restrict__ emb,
                                                 float* __restrict__ hn) {
    int k = blockIdx.x * 256 + threadIdx.x;   // grid 4x256 -> 1024
    const float4* e4 = reinterpret_cast<const float4*>(emb) + (size_t)k * 16;
    float4 a = make_float4(0.f, 0.f, 0.f, 0.f);
#pragma unroll
    for (int i = 0; i < 16; ++i) {
        float4 e = e4[i];
        a.x = fmaf(e.x, e.x, a.x);
        a.y = fmaf(e.y, e.y, a.y);
        a.z = fmaf(e.z, e.z, a.z);
        a.w = fmaf(e.w, e.w, a.w);
    }
    hn[k] = 0.5f * ((a.x + a.y) + (a.z + a.w));
}

// Two tokens per thread, 128 codes per block (8-way K split).
// part = blk>>7, group = blk&127  ->  all 8 parts of a token-group have
// blk % 8 == group % 8 (128*part == 0 mod 8) -> same XCD -> shared x in L2.
// e / hn accesses are wave-uniform -> scalar loads on the SMEM pipe.
__global__ __launch_bounds__(256) void assign_kernel(
    const float* __restrict__ x, const float* __restrict__ emb,
    const float* __restrict__ hn, float* __restrict__ pscore,
    int* __restrict__ pidx) {
    const int part  = blockIdx.x >> 7;     // 0..7
    const int group = blockIdx.x & 127;    // 0..127
    const int t0    = group * 512 + threadIdx.x;
    const int t1    = t0 + 256;
    const int kbase = part * 128;

    const float4* __restrict__ x40 =
        reinterpret_cast<const float4*>(x) + (size_t)t0 * 16;
    const float4* __restrict__ x41 =
        reinterpret_cast<const float4*>(x) + (size_t)t1 * 16;
    float4 xr0[16], xr1[16];
#pragma unroll
    for (int i = 0; i < 16; ++i) xr0[i] = x40[i];
#pragma unroll
    for (int i = 0; i < 16; ++i) xr1[i] = x41[i];

    const float4* __restrict__ e4 =
        reinterpret_cast<const float4*>(emb) + (size_t)kbase * 16;
    const float* __restrict__ hb = hn + kbase;

    float best0 = 3.0e38f, best1 = 3.0e38f;
    int bloc0 = 0, bloc1 = 0;

    for (int kk = 0; kk < 128; kk += 2) {
        const float4* __restrict__ e0 = e4 + (size_t)kk * 16;
        float4 a0 = make_float4(0.f, 0.f, 0.f, 0.f);
        float4 b0 = make_float4(0.f, 0.f, 0.f, 0.f);
        float4 a1 = make_float4(0.f, 0.f, 0.f, 0.f);
        float4 b1 = make_float4(0.f, 0.f, 0.f, 0.f);
#pragma unroll
        for (int i = 0; i < 16; ++i) {
            float4 ea = e0[i];        // uniform -> s_load
            float4 eb = e0[16 + i];   // uniform -> s_load
            float4 x0 = xr0[i];
            float4 x1 = xr1[i];
            a0.x = fmaf(x0.x, ea.x, a0.x);
            a0.y = fmaf(x0.y, ea.y, a0.y);
            a0.z = fmaf(x0.z, ea.z, a0.z);
            a0.w = fmaf(x0.w, ea.w, a0.w);
            b0.x = fmaf(x0.x, eb.x, b0.x);
            b0.y = fmaf(x0.y, eb.y, b0.y);
            b0.z = fmaf(x0.z, eb.z, b0.z);
            b0.w = fmaf(x0.w, eb.w, b0.w);
            a1.x = fmaf(x1.x, ea.x, a1.x);
            a1.y = fmaf(x1.y, ea.y, a1.y);
            a1.z = fmaf(x1.z, ea.z, a1.z);
            a1.w = fmaf(x1.w, ea.w, a1.w);
            b1.x = fmaf(x1.x, eb.x, b1.x);
            b1.y = fmaf(x1.y, eb.y, b1.y);
            b1.z = fmaf(x1.z, eb.z, b1.z);
            b1.w = fmaf(x1.w, eb.w, b1.w);
        }
        float h0 = hb[kk], h1 = hb[kk + 1];
        float s00 = h0 - ((a0.x + a0.y) + (a0.z + a0.w));
        float s01 = h1 - ((b0.x + b0.y) + (b0.z + b0.w));
        float s10 = h0 - ((a1.x + a1.y) + (a1.z + a1.w));
        float s11 = h1 - ((b1.x + b1.y) + (b1.z + b1.w));
        // ascending k + strict < == first-minimum tie-break (jnp.argmin)
        if (s00 < best0) { best0 = s00; bloc0 = kk; }
        if (s01 < best0) { best0 = s01; bloc0 = kk + 1; }
        if (s10 < best1) { best1 = s10; bloc1 = kk; }
        if (s11 < best1) { best1 = s11; bloc1 = kk + 1; }
    }

    pscore[part * N_TOK + t0] = best0;
    pidx  [part * N_TOK + t0] = kbase + bloc0;
    pscore[part * N_TOK + t1] = best1;
    pidx  [part * N_TOK + t1] = kbase + bloc1;
}

// Combine 8 partial candidates; write idx, quantized, loss, counts.
__global__ __launch_bounds__(256) void merge_kernel(
    const float* __restrict__ x, const float* __restrict__ emb,
    const float* __restrict__ pscore, const int* __restrict__ pidx,
    float* __restrict__ counts, int* __restrict__ idx,
    float* __restrict__ loss_sum, float* __restrict__ qout) {
    const int tok = blockIdx.x * 256 + threadIdx.x;

    float bs = pscore[tok];
    int   bi = pidx[tok];
#pragma unroll
    for (int h = 1; h < 8; ++h) {
        float s  = pscore[h * N_TOK + tok];
        int   i2 = pidx[h * N_TOK + tok];
        // later h always has larger idx, so strict < keeps lowest-idx min
        if (s < bs) { bs = s; bi = i2; }
    }
    idx[tok] = bi;

    const float4* x4  = reinterpret_cast<const float4*>(x) + (size_t)tok * 16;
    const float4* eb4 = reinterpret_cast<const float4*>(emb) + (size_t)bi * 16;
    float4* q4 = reinterpret_cast<float4*>(qout) + (size_t)tok * 16;

    float lsum = 0.0f;
#pragma unroll
    for (int i = 0; i < 16; ++i) {
        float4 xv = x4[i];
        float4 e  = eb4[i];
        q4[i] = e;
        float d0 = xv.x - e.x; lsum = fmaf(d0, d0, lsum);
        float d1 = xv.y - e.y; lsum = fmaf(d1, d1, lsum);
        float d2 = xv.z - e.z; lsum = fmaf(d2, d2, lsum);
        float d3 = xv.w - e.w; lsum = fmaf(d3, d3, lsum);
    }

    atomicAdd(&counts[bi], 1.0f);

#pragma unroll
    for (int off = 32; off; off >>= 1) lsum += __shfl_down(lsum, off, 64);
    if ((threadIdx.x & 63) == 0) atomicAdd(loss_sum, lsum);
}

// Segment-sum via scan-gather: block k sums x rows of tokens with idx==k.
// 8 waves/block (8 waves/SIMD device-wide), idx loads unrolled x2 to break
// the dependent-load chain (64 serial iterations instead of 256).
__global__ __launch_bounds__(512) void gather_kernel(
    const float* __restrict__ x, const int* __restrict__ idx,
    float* __restrict__ dw) {
    const int k    = blockIdx.x;          // code
    const int wave = threadIdx.x >> 6;    // 0..7
    const int lane = threadIdx.x & 63;    // dimension

    float acc = 0.0f;
    const int begin = wave * (N_TOK / 8);
    const int end   = begin + (N_TOK / 8);
    for (int base = begin; base < end; base += 128) {
        int mi0 = idx[base + lane];
        int mi1 = idx[base + 64 + lane];
        unsigned long long m0 = __ballot(mi0 == k);
        unsigned long long m1 = __ballot(mi1 == k);
        while (m0) {
            int b = __ffsll((long long)m0) - 1;
            m0 &= m0 - 1;
            acc += x[(size_t)(base + b) * 64 + lane];
        }
        while (m1) {
            int b = __ffsll((long long)m1) - 1;
            m1 &= m1 - 1;
            acc += x[(size_t)(base + 64 + b) * 64 + lane];
        }
    }

    __shared__ float red[8][64];
    red[wave][lane] = acc;
    __syncthreads();
    if (wave == 0) {
        float s = red[0][lane];
#pragma unroll
        for (int w = 1; w < 8; ++w) s += red[w][lane];
        dw[(size_t)k * 64 + lane] = s;
    }
}

// counts-based outputs: new_count, new_usage, scalars (one block, k = tid)
__global__ __launch_bounds__(1024) void finalize1(
    const float* __restrict__ counts, const float* __restrict__ loss_sum,
    const float* __restrict__ ema_count, const float* __restrict__ usage,
    float* __restrict__ out) {
    const int k = threadIdx.x;
    const float cnt = counts[k];
    const float raw = 0.999f * ema_count[k] + 0.001f * cnt;
    const float p = cnt * (1.0f / 65536.0f);
    const float term = p * logf(p + 1e-10f);

    float v1 = raw, v2 = term;
#pragma unroll
    for (int off = 32; off; off >>= 1) {
        v1 += __shfl_down(v1, off, 64);
        v2 += __shfl_down(v2, off, 64);
    }
    __shared__ float r1[16], r2[16];
    __shared__ float s_n, s_plog;
    if ((k & 63) == 0) { r1[k >> 6] = v1; r2[k >> 6] = v2; }
    __syncthreads();
    if (k < 64) {
        float a = (k < 16) ? r1[k] : 0.0f;
        float b = (k < 16) ? r2[k] : 0.0f;
#pragma unroll
        for (int off = 8; off; off >>= 1) {
            a += __shfl_down(a, off, 64);
            b += __shfl_down(b, off, 64);
        }
        if (k == 0) { s_n = a; s_plog = b; }
    }
    __syncthreads();

    const float n = s_n;
    const float smoothed = (raw + 1e-5f) / (n + 1024.0f * 1e-5f) * n;
    out[NC_OFF + k] = smoothed;
    out[NU_OFF + k] = (usage[k] + (cnt > 0.0f ? 1.0f : 0.0f)) * 0.5f;
    if (k == 0) {
        const float lm = loss_sum[0] * (1.0f / 4194304.0f);
        out[SC_OFF + 0] = 0.25f * lm;    // commitment_loss
        out[SC_OFF + 1] = lm;            // codebook_loss
        out[SC_OFF + 2] = expf(-s_plog); // perplexity
    }
}

// new_weight / new_embedding, coalesced elementwise.
__global__ __launch_bounds__(256) void finalize2(
    const float* __restrict__ dw, const float* __restrict__ ema_weight,
    const float* __restrict__ new_count, float* __restrict__ new_weight,
    float* __restrict__ new_embedding) {
    int i = blockIdx.x * 256 + threadIdx.x;   // grid 256x256 -> 65536
    float w = 0.999f * ema_weight[i] + 0.001f * dw[i];
    new_weight[i] = w;
    new_embedding[i] = w / new_count[i >> 6];
}

extern "C" void kernel_launch(void* const* d_in, const int* in_sizes, int n_in,
                              void* d_out, int out_size, void* d_ws, size_t ws_size,
                              hipStream_t stream) {
    const float* x          = (const float*)d_in[0];
    const float* emb        = (const float*)d_in[1];
    const float* ema_count  = (const float*)d_in[2];
    const float* ema_weight = (const float*)d_in[3];
    const float* usage      = (const float*)d_in[4];
    float* out = (float*)d_out;
    float* ws  = (float*)d_ws;

    float* counts = ws + WS_COUNTS;
    float* loss   = ws + WS_LOSS;
    float* hn     = ws + WS_HN;
    float* dw     = ws + WS_DW;
    int*   idx    = (int*)(ws + WS_IDX);
    float* ps     = ws + WS_PS;
    int*   pi     = (int*)(ws + WS_PI);

    // ws is re-poisoned to 0xAA before every timed launch -> zero the
    // atomic regions (counts + loss). Everything else is fully written.
    hipMemsetAsync(ws, 0, 1025 * sizeof(float), stream);

    hn_kernel<<<4, 256, 0, stream>>>(emb, hn);
    assign_kernel<<<1024, 256, 0, stream>>>(x, emb, hn, ps, pi);
    merge_kernel<<<256, 256, 0, stream>>>(x, emb, ps, pi, counts, idx, loss,
                                          out + Q_OFF);
    gather_kernel<<<1024, 512, 0, stream>>>(x, idx, dw);
    finalize1<<<1, 1024, 0, stream>>>(counts, loss, ema_count, usage, out);
    finalize2<<<256, 256, 0, stream>>>(dw, ema_weight, out + NC_OFF,
                                       out + NW_OFF, out + NE_OFF);
}